// Round 12
// baseline (128.540 us; speedup 1.0000x reference)
//
#include <hip/hip_runtime.h>
#include <cmath>

namespace {

constexpr int kDim = 5;
constexpr int kSave = 64;
constexpr int kTraj = 16;      // trajectories per stream (= MFMA M)
constexpr int kStreams = 2;    // independent RK solves per block (latency hiding)
constexpr int kThreads = 256;  // 4 waves; wave w owns neuron tile [16w,16w+16)
constexpr int kMaxSteps = 64;
constexpr int HS = 72;         // f16 stride: activation planes (144 B)
constexpr int SD = 8;          // f32 stride: small state rows

typedef _Float16 half8 __attribute__((ext_vector_type(8)));
typedef float f32x4 __attribute__((ext_vector_type(4)));

__device__ __forceinline__ float softplusf(float x) {
  return fmaxf(x, 0.0f) + __logf(1.0f + __expf(-fabsf(x)));
}

__global__ __launch_bounds__(kThreads, 1)
void node_tsit5_kernel(const float* __restrict__ gy0,
                       const float* __restrict__ gte,
                       const float* __restrict__ gW1, const float* __restrict__ gb1,
                       const float* __restrict__ gW2, const float* __restrict__ gb2,
                       const float* __restrict__ gW3, const float* __restrict__ gb3,
                       const float* __restrict__ gW4, const float* __restrict__ gb4,
                       float* __restrict__ out) {
  const float A21 = 0.161f;
  const float A31 = -0.008480655492356989f, A32 = 0.335480655492357f;
  const float A41 = 2.8971530571054935f, A42 = -6.359448489975075f, A43 = 4.3622954328695815f;
  const float A51 = 5.325864828439257f, A52 = -11.748883564062828f, A53 = 7.4955393428898365f,
              A54 = -0.09249506636175525f;
  const float A61 = 5.86145544294642f, A62 = -12.92096931784711f, A63 = 8.159367898576159f,
              A64 = -0.071584973281401f, A65 = -0.028269050394068383f;
  const float B1 = 0.09646076681806523f, B2 = 0.01f, B3 = 0.4798896504144996f,
              B4 = 1.379008574103742f, B5 = -3.290069515436081f, B6 = 2.324710524099774f;
  const float E1 = -0.00178001105222577714f, E2 = -0.0008164344596567469f,
              E3 = 0.007880878010261995f, E4 = -0.1447110071732629f, E5 = 0.5823571654525552f,
              E6 = -0.45808210592918697f, E7 = 0.015151515151515152f;

  // per-stream activation planes (rotation h0->h1->h2, 3 shared barriers/eval)
  __shared__ __align__(16) _Float16 h0[kStreams][kTraj * HS], l0[kStreams][kTraj * HS];
  __shared__ __align__(16) _Float16 h1[kStreams][kTraj * HS], l1[kStreams][kTraj * HS];
  __shared__ __align__(16) _Float16 h2[kStreams][kTraj * HS], l2[kStreams][kTraj * HS];
  __shared__ float sTe[kSave];
  __shared__ float sY[kStreams][kTraj * SD], sYN[kStreams][kTraj * SD];
  __shared__ float sK1[kStreams][kTraj * SD], sK7[kStreams][kTraj * SD];
  __shared__ float ctT[kStreams][kTraj], ctH[kStreams][kTraj];
  __shared__ float ctN[kStreams][kTraj], ctO[kStreams][kTraj];

  const int tid = threadIdx.x;
  const int bid = blockIdx.x;
  const int w = tid >> 6;          // wave id = neuron tile
  const int ln = tid & 63;
  const int quad = ln >> 4;
  const int col = ln & 15;
  const int row0 = quad * 4;       // this lane's C-layout trajectories: row0+r
  const int nn = (w << 4) | col;
  const bool cact = col < kDim;    // C-lane carries dim d = col
  const bool w0 = (w == 0);

  // ---- one-time: weight B-frags + biases + fused M = W1*W4 (stream-shared) ----
  half8 w2h[2], w3h[2], w4h[2], mfh[2];
  float w1r[kDim];
  #pragma unroll
  for (int d = 0; d < kDim; ++d) w1r[d] = gW1[nn * 5 + d];
  #pragma unroll
  for (int kf = 0; kf < 2; ++kf)
    #pragma unroll
    for (int j = 0; j < 8; ++j) {
      int kk2 = kf * 32 + quad * 8 + j;
      w2h[kf][j] = (_Float16)gW2[nn * 64 + kk2];
      w3h[kf][j] = (_Float16)gW3[nn * 64 + kk2];
      w4h[kf][j] = cact ? (_Float16)gW4[col * 64 + kk2] : (_Float16)0.0f;
      float m = 0.0f;
      #pragma unroll
      for (int d = 0; d < kDim; ++d) m = fmaf(w1r[d], gW4[d * 64 + kk2], m);
      mfh[kf][j] = (_Float16)m;
    }
  const float c1 = gb1[nn], c2 = gb2[nn], c3 = gb3[nn];
  const float c4 = cact ? gb4[col] : 0.0f;   // => k cols>=5 are exactly 0
  float cu = 0.0f;                            // (W1*b4)[nn]
  #pragma unroll
  for (int d = 0; d < kDim; ++d) cu = fmaf(w1r[d], gb4[d], cu);

  // ---- init LDS ----
  if (tid < kSave) sTe[tid] = gte[tid];
  if (tid < kStreams * kTraj * kDim) {   // sY for the y0 output fill
    int s = tid / (kTraj * kDim), rem = tid % (kTraj * kDim);   // FIX: 80/stream
    int t = rem & 15, d = rem >> 4;
    sY[s][t * SD + d] = gy0[(size_t)(bid * kStreams * kTraj + s * kTraj + t) * kDim + d];
  }
  {
    float* ob = out + (size_t)bid * kStreams * kTraj * kSave * kDim;
    for (int idx = tid; idx < kStreams * kTraj * kSave * kDim; idx += kThreads)
      ob[idx] = 0.0f;
  }

  // per-stream state: y (replicated across waves) + p_y = W1*y + b1 (per tile)
  f32x4 syr[kStreams], synr[kStreams], kkS[kStreams][7], uuS[kStreams][7], p_y[kStreams];
  #pragma unroll
  for (int s = 0; s < kStreams; ++s) {
    syr[s] = f32x4{0, 0, 0, 0};
    #pragma unroll
    for (int r = 0; r < 4; ++r) {
      const float* yr = gy0 + (size_t)(bid * kStreams * kTraj + s * kTraj + row0 + r) * kDim;
      float acc = c1;
      #pragma unroll
      for (int d = 0; d < kDim; ++d) acc = fmaf(w1r[d], yr[d], acc);
      p_y[s][r] = acc;
      if (cact) syr[s][r] = yr[col];
    }
  }
  __syncthreads();

  const float t0v = sTe[0];
  const float t1v = sTe[kSave - 1];

  // saves at/before t0 get y0 (same-lane overwrite later -> program order)
  {
    int tt = tid & 15, gg = tid >> 4;
    #pragma unroll
    for (int s = 0; s < kStreams; ++s) {
      float yv[kDim];
      #pragma unroll
      for (int d = 0; d < kDim; ++d) yv[d] = sY[s][tt * SD + d];
      #pragma unroll
      for (int q = 0; q < 4; ++q) {
        int n = 4 * gg + q;
        if (sTe[n] <= t0v + 1e-6f) {
          float* op = out +
              ((size_t)(bid * kStreams * kTraj + s * kTraj + tt) * kSave + n) * kDim;
          #pragma unroll
          for (int d = 0; d < kDim; ++d) op[d] = yv[d];
        }
      }
    }
  }

  // ---- dual-stream fused eval; 3 shared barriers; per-stream k,u outputs ----
  auto evalF2 = [&](const f32x4 pre1[kStreams], f32x4 kOut[kStreams],
                    f32x4 uOut[kStreams]) {
    #pragma unroll
    for (int s = 0; s < kStreams; ++s)
      #pragma unroll
      for (int r = 0; r < 4; ++r) {   // stage A (VALU): softplus -> h0/l0
        float sv = softplusf(pre1[s][r]);
        _Float16 hi = (_Float16)sv;
        h0[s][(row0 + r) * HS + nn] = hi;
        l0[s][(row0 + r) * HS + nn] = (_Float16)(sv - (float)hi);
      }
    __syncthreads();   // b1
    #pragma unroll
    for (int s = 0; s < kStreams; ++s) {  // L2
      half8 ah0 = *(const half8*)(h0[s] + col * HS + quad * 8);
      half8 ah1 = *(const half8*)(h0[s] + col * HS + 32 + quad * 8);
      half8 al0 = *(const half8*)(l0[s] + col * HS + quad * 8);
      half8 al1 = *(const half8*)(l0[s] + col * HS + 32 + quad * 8);
      f32x4 a = {c2, c2, c2, c2};
      f32x4 b = {0, 0, 0, 0};
      a = __builtin_amdgcn_mfma_f32_16x16x32_f16(ah0, w2h[0], a, 0, 0, 0);
      b = __builtin_amdgcn_mfma_f32_16x16x32_f16(al0, w2h[0], b, 0, 0, 0);
      a = __builtin_amdgcn_mfma_f32_16x16x32_f16(ah1, w2h[1], a, 0, 0, 0);
      b = __builtin_amdgcn_mfma_f32_16x16x32_f16(al1, w2h[1], b, 0, 0, 0);
      a += b;
      #pragma unroll
      for (int r = 0; r < 4; ++r) {
        float sv = softplusf(a[r]);
        _Float16 hi = (_Float16)sv;
        h1[s][(row0 + r) * HS + nn] = hi;
        l1[s][(row0 + r) * HS + nn] = (_Float16)(sv - (float)hi);
      }
    }
    __syncthreads();   // b2
    #pragma unroll
    for (int s = 0; s < kStreams; ++s) {  // L3
      half8 ah0 = *(const half8*)(h1[s] + col * HS + quad * 8);
      half8 ah1 = *(const half8*)(h1[s] + col * HS + 32 + quad * 8);
      half8 al0 = *(const half8*)(l1[s] + col * HS + quad * 8);
      half8 al1 = *(const half8*)(l1[s] + col * HS + 32 + quad * 8);
      f32x4 a = {c3, c3, c3, c3};
      f32x4 b = {0, 0, 0, 0};
      a = __builtin_amdgcn_mfma_f32_16x16x32_f16(ah0, w3h[0], a, 0, 0, 0);
      b = __builtin_amdgcn_mfma_f32_16x16x32_f16(al0, w3h[0], b, 0, 0, 0);
      a = __builtin_amdgcn_mfma_f32_16x16x32_f16(ah1, w3h[1], a, 0, 0, 0);
      b = __builtin_amdgcn_mfma_f32_16x16x32_f16(al1, w3h[1], b, 0, 0, 0);
      a += b;
      #pragma unroll
      for (int r = 0; r < 4; ++r) {
        float sv = softplusf(a[r]);
        _Float16 hi = (_Float16)sv;
        h2[s][(row0 + r) * HS + nn] = hi;
        l2[s][(row0 + r) * HS + nn] = (_Float16)(sv - (float)hi);
      }
    }
    __syncthreads();   // b3
    #pragma unroll
    for (int s = 0; s < kStreams; ++s) {  // final: k (cols<5) + u (this tile)
      half8 ah0 = *(const half8*)(h2[s] + col * HS + quad * 8);
      half8 ah1 = *(const half8*)(h2[s] + col * HS + 32 + quad * 8);
      half8 al0 = *(const half8*)(l2[s] + col * HS + quad * 8);
      half8 al1 = *(const half8*)(l2[s] + col * HS + 32 + quad * 8);
      f32x4 ka = {c4, c4, c4, c4};
      f32x4 kb = {0, 0, 0, 0};
      f32x4 ua = {cu, cu, cu, cu};
      f32x4 ub = {0, 0, 0, 0};
      ka = __builtin_amdgcn_mfma_f32_16x16x32_f16(ah0, w4h[0], ka, 0, 0, 0);
      kb = __builtin_amdgcn_mfma_f32_16x16x32_f16(al0, w4h[0], kb, 0, 0, 0);
      ua = __builtin_amdgcn_mfma_f32_16x16x32_f16(ah0, mfh[0], ua, 0, 0, 0);
      ub = __builtin_amdgcn_mfma_f32_16x16x32_f16(al0, mfh[0], ub, 0, 0, 0);
      ka = __builtin_amdgcn_mfma_f32_16x16x32_f16(ah1, w4h[1], ka, 0, 0, 0);
      kb = __builtin_amdgcn_mfma_f32_16x16x32_f16(al1, w4h[1], kb, 0, 0, 0);
      ua = __builtin_amdgcn_mfma_f32_16x16x32_f16(ah1, mfh[1], ua, 0, 0, 0);
      ub = __builtin_amdgcn_mfma_f32_16x16x32_f16(al1, mfh[1], ub, 0, 0, 0);
      kOut[s] = ka + kb;
      uOut[s] = ua + ub;
    }
  };

  {
    f32x4 k0[kStreams], u0[kStreams];
    evalF2(p_y, k0, u0);   // k1 = f(y0); FSAL thereafter
    #pragma unroll
    for (int s = 0; s < kStreams; ++s) { kkS[s][0] = k0[s]; uuS[s][0] = u0[s]; }
  }

  f32x4 tcur[kStreams], hcur[kStreams];
  #pragma unroll
  for (int s = 0; s < kStreams; ++s) {
    tcur[s] = f32x4{t0v, t0v, t0v, t0v};
    hcur[s] = f32x4{0.1f, 0.1f, 0.1f, 0.1f};
  }

  for (int step = 0; step < kMaxSteps; ++step) {
    // ---- head: pure registers ----
    f32x4 hcs[kStreams], tOldr[kStreams];
    bool dnr[kStreams][4];
    bool allA = true;
    #pragma unroll
    for (int s = 0; s < kStreams; ++s)
      #pragma unroll
      for (int r = 0; r < 4; ++r) {
        bool d = tcur[s][r] >= t1v - 1e-6f;
        dnr[s][r] = d;
        allA &= d;
        hcs[s][r] = d ? 0.0f : fminf(hcur[s][r], t1v - tcur[s][r]);
        tOldr[s][r] = tcur[s][r];
      }
    if (__ballot(allA) == ~0ull) break;   // all 32 trajectories done (uniform)

    f32x4 p1[kStreams], kO[kStreams], uO[kStreams];

    #pragma unroll
    for (int s = 0; s < kStreams; ++s)
      #pragma unroll
      for (int r = 0; r < 4; ++r)
        p1[s][r] = fmaf(hcs[s][r], A21 * uuS[s][0][r], p_y[s][r]);
    evalF2(p1, kO, uO);
    #pragma unroll
    for (int s = 0; s < kStreams; ++s) { kkS[s][1] = kO[s]; uuS[s][1] = uO[s]; }

    #pragma unroll
    for (int s = 0; s < kStreams; ++s)
      #pragma unroll
      for (int r = 0; r < 4; ++r)
        p1[s][r] = fmaf(hcs[s][r], fmaf(A32, uuS[s][1][r], A31 * uuS[s][0][r]), p_y[s][r]);
    evalF2(p1, kO, uO);
    #pragma unroll
    for (int s = 0; s < kStreams; ++s) { kkS[s][2] = kO[s]; uuS[s][2] = uO[s]; }

    #pragma unroll
    for (int s = 0; s < kStreams; ++s)
      #pragma unroll
      for (int r = 0; r < 4; ++r)
        p1[s][r] = fmaf(hcs[s][r], fmaf(A43, uuS[s][2][r],
                    fmaf(A42, uuS[s][1][r], A41 * uuS[s][0][r])), p_y[s][r]);
    evalF2(p1, kO, uO);
    #pragma unroll
    for (int s = 0; s < kStreams; ++s) { kkS[s][3] = kO[s]; uuS[s][3] = uO[s]; }

    #pragma unroll
    for (int s = 0; s < kStreams; ++s)
      #pragma unroll
      for (int r = 0; r < 4; ++r)
        p1[s][r] = fmaf(hcs[s][r], fmaf(A54, uuS[s][3][r], fmaf(A53, uuS[s][2][r],
                    fmaf(A52, uuS[s][1][r], A51 * uuS[s][0][r]))), p_y[s][r]);
    evalF2(p1, kO, uO);
    #pragma unroll
    for (int s = 0; s < kStreams; ++s) { kkS[s][4] = kO[s]; uuS[s][4] = uO[s]; }

    #pragma unroll
    for (int s = 0; s < kStreams; ++s)
      #pragma unroll
      for (int r = 0; r < 4; ++r)
        p1[s][r] = fmaf(hcs[s][r], fmaf(A65, uuS[s][4][r], fmaf(A64, uuS[s][3][r],
                    fmaf(A63, uuS[s][2][r], fmaf(A62, uuS[s][1][r],
                    A61 * uuS[s][0][r])))), p_y[s][r]);
    evalF2(p1, kO, uO);
    #pragma unroll
    for (int s = 0; s < kStreams; ++s) { kkS[s][5] = kO[s]; uuS[s][5] = uO[s]; }

    f32x4 bu[kStreams];
    #pragma unroll
    for (int s = 0; s < kStreams; ++s)
      #pragma unroll
      for (int r = 0; r < 4; ++r) {
        bu[s][r] = fmaf(B6, uuS[s][5][r], fmaf(B5, uuS[s][4][r], fmaf(B4, uuS[s][3][r],
                   fmaf(B3, uuS[s][2][r], fmaf(B2, uuS[s][1][r], B1 * uuS[s][0][r])))));
        synr[s][r] = fmaf(hcs[s][r], fmaf(B6, kkS[s][5][r], fmaf(B5, kkS[s][4][r],
                     fmaf(B4, kkS[s][3][r], fmaf(B3, kkS[s][2][r],
                     fmaf(B2, kkS[s][1][r], B1 * kkS[s][0][r]))))), syr[s][r]);
        p1[s][r] = fmaf(hcs[s][r], bu[s][r], p_y[s][r]);
      }
    // early-stash: interp state known pre-k7; drains behind evalF's barriers
    if (w0 && cact) {
      #pragma unroll
      for (int s = 0; s < kStreams; ++s)
        #pragma unroll
        for (int r = 0; r < 4; ++r) {
          int o = (row0 + r) * SD + col;
          sY[s][o] = syr[s][r];
          sYN[s][o] = synr[s][r];
          sK1[s][o] = kkS[s][0][r];
        }
    }
    evalF2(p1, kO, uO);   // k7 (FSAL)
    #pragma unroll
    for (int s = 0; s < kStreams; ++s) { kkS[s][6] = kO[s]; uuS[s][6] = uO[s]; }

    // ---- error norm + controller (registers, all lanes, per stream) ----
    bool okr[kStreams][4];
    #pragma unroll
    for (int s = 0; s < kStreams; ++s) {
      f32x4 rr2;
      #pragma unroll
      for (int r = 0; r < 4; ++r) {
        float err = hcs[s][r] * fmaf(E7, kkS[s][6][r], fmaf(E6, kkS[s][5][r],
                    fmaf(E5, kkS[s][4][r], fmaf(E4, kkS[s][3][r], fmaf(E3, kkS[s][2][r],
                    fmaf(E2, kkS[s][1][r], E1 * kkS[s][0][r]))))));
        float sc = fmaf(1e-3f, fmaxf(fabsf(syr[s][r]), fabsf(synr[s][r])), 1e-6f);
        float rr = err / sc;
        rr2[r] = cact ? rr * rr : 0.0f;
      }
      #pragma unroll
      for (int m = 1; m < 16; m <<= 1) {
        #pragma unroll
        for (int r = 0; r < 4; ++r) rr2[r] += __shfl_xor(rr2[r], m, 64);
      }
      #pragma unroll
      for (int r = 0; r < 4; ++r) {
        float enorm = sqrtf(rr2[r] / 5.0f);
        float enc = fmaxf(enorm, 1e-10f);
        bool accept = enorm <= 1.0f;
        float factor = fminf(fmaxf(0.9f * __expf(-0.2f * __logf(enc)), 0.2f), 10.0f);
        bool ok = accept && !dnr[s][r];
        okr[s][r] = ok;
        tcur[s][r] = ok ? tcur[s][r] + hcs[s][r] : tcur[s][r];
        hcur[s][r] = dnr[s][r] ? hcur[s][r] : hcs[s][r] * factor;
      }
    }

    // ---- small stash: k7 + control; ONE tail barrier ----
    if (w0 && cact) {
      #pragma unroll
      for (int s = 0; s < kStreams; ++s)
        #pragma unroll
        for (int r = 0; r < 4; ++r) sK7[s][(row0 + r) * SD + col] = kkS[s][6][r];
    }
    if (w0 && col == 0) {
      #pragma unroll
      for (int s = 0; s < kStreams; ++s)
        #pragma unroll
        for (int r = 0; r < 4; ++r) {
          int m2 = row0 + r;
          ctT[s][m2] = tOldr[s][r];
          ctH[s][m2] = hcs[s][r];
          ctN[s][m2] = tcur[s][r];
          ctO[s][m2] = okr[s][r] ? 1.0f : 0.0f;
        }
    }
    __syncthreads();

    // ---- cubic Hermite interpolation, both streams ----
    {
      int tt = tid & 15, gg = tid >> 4;
      #pragma unroll
      for (int s = 0; s < kStreams; ++s) {
        if (ctO[s][tt] != 0.0f) {
          float tOld = ctT[s][tt], hcv = ctH[s][tt], tNew = ctN[s][tt];
          float inv = 1.0f / fmaxf(hcv, 1e-12f);
          float yv[kDim], ynv[kDim], k1v[kDim], k7v[kDim];
          #pragma unroll
          for (int d = 0; d < kDim; ++d) {
            yv[d] = sY[s][tt * SD + d];
            ynv[d] = sYN[s][tt * SD + d];
            k1v[d] = hcv * sK1[s][tt * SD + d];
            k7v[d] = hcv * sK7[s][tt * SD + d];
          }
          #pragma unroll
          for (int q = 0; q < 4; ++q) {
            int n = 4 * gg + q;
            float te = sTe[n];
            if (te > tOld && te <= tNew + 1e-6f) {
              float sx = (te - tOld) * inv;
              float s2 = sx * sx, s3 = s2 * sx;
              float h00 = 2.f * s3 - 3.f * s2 + 1.f;
              float h10 = s3 - 2.f * s2 + sx;
              float h01 = -2.f * s3 + 3.f * s2;
              float h11 = s3 - s2;
              float* op = out +
                  ((size_t)(bid * kStreams * kTraj + s * kTraj + tt) * kSave + n) * kDim;
              #pragma unroll
              for (int d = 0; d < kDim; ++d)
                op[d] = h00 * yv[d] + h10 * k1v[d] + h01 * ynv[d] + h11 * k7v[d];
            }
          }
        }
      }
    }

    // ---- FSAL + state update (pure registers) ----
    #pragma unroll
    for (int s = 0; s < kStreams; ++s)
      #pragma unroll
      for (int r = 0; r < 4; ++r) {
        if (okr[s][r]) {
          syr[s][r] = synr[s][r];
          kkS[s][0][r] = kkS[s][6][r];
          uuS[s][0][r] = uuS[s][6][r];
          p_y[s][r] = fmaf(hcs[s][r], bu[s][r], p_y[s][r]);
        }
      }
  }
}

}  // namespace

extern "C" void kernel_launch(void* const* d_in, const int* in_sizes, int n_in,
                              void* d_out, int out_size, void* d_ws, size_t ws_size,
                              hipStream_t stream) {
  const float* y0 = (const float*)d_in[0];
  const float* te = (const float*)d_in[1];
  const float* W1 = (const float*)d_in[2];
  const float* b1 = (const float*)d_in[3];
  const float* W2 = (const float*)d_in[4];
  const float* b2 = (const float*)d_in[5];
  const float* W3 = (const float*)d_in[6];
  const float* b3 = (const float*)d_in[7];
  const float* W4 = (const float*)d_in[8];
  const float* b4 = (const float*)d_in[9];
  float* out = (float*)d_out;

  const int batch = in_sizes[0] / kDim;              // 4096
  const int blocks = batch / (kTraj * kStreams);     // 128 blocks x 32 traj
  hipLaunchKernelGGL(node_tsit5_kernel, dim3(blocks), dim3(kThreads), 0, stream,
                     y0, te, W1, b1, W2, b2, W3, b3, W4, b4, out);
}

// Round 13
// 118.085 us; speedup vs baseline: 1.0885x; 1.0885x over previous
//
#include <hip/hip_runtime.h>
#include <cmath>

namespace {

constexpr int kDim = 5;
constexpr int kSave = 64;
constexpr int kTraj = 8;       // valid trajectories per block (M rows 0..7)
constexpr int kRows = 16;      // MFMA M (rows 8..15 are don't-care)
constexpr int kThreads = 256;  // 4 waves; wave w owns neuron tile [16w,16w+16)
constexpr int kMaxSteps = 64;
constexpr int HS = 72;         // f16 stride: activation planes (144 B)
constexpr int SD = 8;          // f32 stride: small state rows

typedef _Float16 half8 __attribute__((ext_vector_type(8)));
typedef float f32x4 __attribute__((ext_vector_type(4)));

__device__ __forceinline__ float softplusf(float x) {
  return fmaxf(x, 0.0f) + __logf(1.0f + __expf(-fabsf(x)));
}

__global__ __launch_bounds__(kThreads, 2)   // 2 blocks/CU co-resident (TLP)
void node_tsit5_kernel(const float* __restrict__ gy0,
                       const float* __restrict__ gte,
                       const float* __restrict__ gW1, const float* __restrict__ gb1,
                       const float* __restrict__ gW2, const float* __restrict__ gb2,
                       const float* __restrict__ gW3, const float* __restrict__ gb3,
                       const float* __restrict__ gW4, const float* __restrict__ gb4,
                       float* __restrict__ out) {
  const float A21 = 0.161f;
  const float A31 = -0.008480655492356989f, A32 = 0.335480655492357f;
  const float A41 = 2.8971530571054935f, A42 = -6.359448489975075f, A43 = 4.3622954328695815f;
  const float A51 = 5.325864828439257f, A52 = -11.748883564062828f, A53 = 7.4955393428898365f,
              A54 = -0.09249506636175525f;
  const float A61 = 5.86145544294642f, A62 = -12.92096931784711f, A63 = 8.159367898576159f,
              A64 = -0.071584973281401f, A65 = -0.028269050394068383f;
  const float B1 = 0.09646076681806523f, B2 = 0.01f, B3 = 0.4798896504144996f,
              B4 = 1.379008574103742f, B5 = -3.290069515436081f, B6 = 2.324710524099774f;
  const float E1 = -0.00178001105222577714f, E2 = -0.0008164344596567469f,
              E3 = 0.007880878010261995f, E4 = -0.1447110071732629f, E5 = 0.5823571654525552f,
              E6 = -0.45808210592918697f, E7 = 0.015151515151515152f;

  // LDS planes sized for the full 16 MFMA rows (rows 8..15 carry garbage but
  // stay in-bounds and row-contained through every MFMA).
  __shared__ __align__(16) _Float16 h0[kRows * HS], l0[kRows * HS];
  __shared__ __align__(16) _Float16 h1[kRows * HS], l1[kRows * HS];
  __shared__ __align__(16) _Float16 h2[kRows * HS], l2[kRows * HS];
  __shared__ float sTe[kSave];
  __shared__ float sY[kRows * SD], sYN[kRows * SD], sK1[kRows * SD], sK7[kRows * SD];
  __shared__ float ctT[kRows], ctH[kRows], ctN[kRows], ctO[kRows];

  const int tid = threadIdx.x;
  const int bid = blockIdx.x;
  const int w = tid >> 6;          // wave id = neuron tile
  const int ln = tid & 63;
  const int quad = ln >> 4;
  const int col = ln & 15;
  const int row0 = quad * 4;       // this lane's C-layout trajectories: row0+r
  const int nn = (w << 4) | col;
  const bool cact = col < kDim;    // C-lane carries dim d = col
  const bool w0 = (w == 0);

  // ---- one-time: weight B-frags + biases + fused M = W1*W4 ----
  half8 w2h[2], w3h[2], w4h[2], mfh[2];
  float w1r[kDim];
  #pragma unroll
  for (int d = 0; d < kDim; ++d) w1r[d] = gW1[nn * 5 + d];
  #pragma unroll
  for (int kf = 0; kf < 2; ++kf)
    #pragma unroll
    for (int j = 0; j < 8; ++j) {
      int kk2 = kf * 32 + quad * 8 + j;
      w2h[kf][j] = (_Float16)gW2[nn * 64 + kk2];
      w3h[kf][j] = (_Float16)gW3[nn * 64 + kk2];
      w4h[kf][j] = cact ? (_Float16)gW4[col * 64 + kk2] : (_Float16)0.0f;
      float m = 0.0f;
      #pragma unroll
      for (int d = 0; d < kDim; ++d) m = fmaf(w1r[d], gW4[d * 64 + kk2], m);
      mfh[kf][j] = (_Float16)m;
    }
  const float c1 = gb1[nn], c2 = gb2[nn], c3 = gb3[nn];
  const float c4 = cact ? gb4[col] : 0.0f;   // => k cols>=5 are exactly 0
  float cu = 0.0f;                            // (W1*b4)[nn]
  #pragma unroll
  for (int d = 0; d < kDim; ++d) cu = fmaf(w1r[d], gb4[d], cu);

  // ---- init LDS ----
  if (tid < kSave) sTe[tid] = gte[tid];
  if (tid < kTraj * kDim) {   // sY for the y0 output fill; t = tid&7, d = tid>>3
    int t = tid & 7, d = tid >> 3;
    sY[t * SD + d] = gy0[(size_t)(bid * kTraj + t) * kDim + d];
  }
  {
    float* ob = out + (size_t)bid * kTraj * kSave * kDim;
    for (int idx = tid; idx < kTraj * kSave * kDim; idx += kThreads) ob[idx] = 0.0f;
  }

  // y-state (replicated across waves) + p_y = W1*y + b1 (per wave tile, f32).
  // Rows >= kTraj: clamp the gy0 read (finite garbage; ok/done masks it).
  f32x4 syr = {0, 0, 0, 0}, synr = {0, 0, 0, 0}, kk[7], uu[7], p_y;
  #pragma unroll
  for (int r = 0; r < 4; ++r) {
    int tr = row0 + r;
    int trc = tr < kTraj ? tr : (kTraj - 1);
    const float* yr = gy0 + (size_t)(bid * kTraj + trc) * kDim;
    float acc = c1;
    #pragma unroll
    for (int d = 0; d < kDim; ++d) acc = fmaf(w1r[d], yr[d], acc);
    p_y[r] = acc;
    if (cact) syr[r] = yr[col];
  }
  __syncthreads();

  const float t0v = sTe[0];
  const float t1v = sTe[kSave - 1];

  // saves at/before t0 get y0 (same-lane overwrite later -> program order)
  {
    int tt = tid & 7, gg = tid >> 3;    // 8 trajs x 32 groups x 2 saves
    float yv[kDim];
    #pragma unroll
    for (int d = 0; d < kDim; ++d) yv[d] = sY[tt * SD + d];
    #pragma unroll
    for (int q = 0; q < 2; ++q) {
      int n = 2 * gg + q;
      if (sTe[n] <= t0v + 1e-6f) {
        float* op = out + ((size_t)(bid * kTraj + tt) * kSave + n) * kDim;
        #pragma unroll
        for (int d = 0; d < kDim; ++d) op[d] = yv[d];
      }
    }
  }

  // ---- fused eval: pre1 (C-regs) -> k (cols<5) and u (all cols); 3 barriers ----
  auto evalF = [&](f32x4 pre1, f32x4& kOut, f32x4& uOut) {
    #pragma unroll
    for (int r = 0; r < 4; ++r) {   // stage A (VALU): softplus(pre1) -> h0/l0
      float s = softplusf(pre1[r]);
      _Float16 hi = (_Float16)s;
      h0[(row0 + r) * HS + nn] = hi;
      l0[(row0 + r) * HS + nn] = (_Float16)(s - (float)hi);
    }
    __syncthreads();   // b1
    {  // L2: h0/l0 -> h1/l1
      half8 ah0 = *(const half8*)(h0 + col * HS + quad * 8);
      half8 ah1 = *(const half8*)(h0 + col * HS + 32 + quad * 8);
      half8 al0 = *(const half8*)(l0 + col * HS + quad * 8);
      half8 al1 = *(const half8*)(l0 + col * HS + 32 + quad * 8);
      f32x4 a = {c2, c2, c2, c2};
      f32x4 b = {0, 0, 0, 0};
      a = __builtin_amdgcn_mfma_f32_16x16x32_f16(ah0, w2h[0], a, 0, 0, 0);
      b = __builtin_amdgcn_mfma_f32_16x16x32_f16(al0, w2h[0], b, 0, 0, 0);
      a = __builtin_amdgcn_mfma_f32_16x16x32_f16(ah1, w2h[1], a, 0, 0, 0);
      b = __builtin_amdgcn_mfma_f32_16x16x32_f16(al1, w2h[1], b, 0, 0, 0);
      a += b;
      #pragma unroll
      for (int r = 0; r < 4; ++r) {
        float s = softplusf(a[r]);
        _Float16 hi = (_Float16)s;
        h1[(row0 + r) * HS + nn] = hi;
        l1[(row0 + r) * HS + nn] = (_Float16)(s - (float)hi);
      }
    }
    __syncthreads();   // b2
    {  // L3: h1/l1 -> h2/l2
      half8 ah0 = *(const half8*)(h1 + col * HS + quad * 8);
      half8 ah1 = *(const half8*)(h1 + col * HS + 32 + quad * 8);
      half8 al0 = *(const half8*)(l1 + col * HS + quad * 8);
      half8 al1 = *(const half8*)(l1 + col * HS + 32 + quad * 8);
      f32x4 a = {c3, c3, c3, c3};
      f32x4 b = {0, 0, 0, 0};
      a = __builtin_amdgcn_mfma_f32_16x16x32_f16(ah0, w3h[0], a, 0, 0, 0);
      b = __builtin_amdgcn_mfma_f32_16x16x32_f16(al0, w3h[0], b, 0, 0, 0);
      a = __builtin_amdgcn_mfma_f32_16x16x32_f16(ah1, w3h[1], a, 0, 0, 0);
      b = __builtin_amdgcn_mfma_f32_16x16x32_f16(al1, w3h[1], b, 0, 0, 0);
      a += b;
      #pragma unroll
      for (int r = 0; r < 4; ++r) {
        float s = softplusf(a[r]);
        _Float16 hi = (_Float16)s;
        h2[(row0 + r) * HS + nn] = hi;
        l2[(row0 + r) * HS + nn] = (_Float16)(s - (float)hi);
      }
    }
    __syncthreads();   // b3
    {  // final: k = W4*h3 + b4 (cols<5) and u = M*h3 + W1*b4 (this tile)
      half8 ah0 = *(const half8*)(h2 + col * HS + quad * 8);
      half8 ah1 = *(const half8*)(h2 + col * HS + 32 + quad * 8);
      half8 al0 = *(const half8*)(l2 + col * HS + quad * 8);
      half8 al1 = *(const half8*)(l2 + col * HS + 32 + quad * 8);
      f32x4 ka = {c4, c4, c4, c4};
      f32x4 kb = {0, 0, 0, 0};
      f32x4 ua = {cu, cu, cu, cu};
      f32x4 ub = {0, 0, 0, 0};
      ka = __builtin_amdgcn_mfma_f32_16x16x32_f16(ah0, w4h[0], ka, 0, 0, 0);
      kb = __builtin_amdgcn_mfma_f32_16x16x32_f16(al0, w4h[0], kb, 0, 0, 0);
      ua = __builtin_amdgcn_mfma_f32_16x16x32_f16(ah0, mfh[0], ua, 0, 0, 0);
      ub = __builtin_amdgcn_mfma_f32_16x16x32_f16(al0, mfh[0], ub, 0, 0, 0);
      ka = __builtin_amdgcn_mfma_f32_16x16x32_f16(ah1, w4h[1], ka, 0, 0, 0);
      kb = __builtin_amdgcn_mfma_f32_16x16x32_f16(al1, w4h[1], kb, 0, 0, 0);
      ua = __builtin_amdgcn_mfma_f32_16x16x32_f16(ah1, mfh[1], ua, 0, 0, 0);
      ub = __builtin_amdgcn_mfma_f32_16x16x32_f16(al1, mfh[1], ub, 0, 0, 0);
      kOut = ka + kb;
      uOut = ua + ub;
    }
  };

  evalF(p_y, kk[0], uu[0]);   // k1 = f(y0); FSAL thereafter

  // control state in registers; rows >= kTraj start "done" (tcur = t1v)
  f32x4 tcur, hcur = {0.1f, 0.1f, 0.1f, 0.1f};
  #pragma unroll
  for (int r = 0; r < 4; ++r) tcur[r] = (row0 + r < kTraj) ? t0v : t1v;

  for (int step = 0; step < kMaxSteps; ++step) {
    // ---- head: pure registers, no barrier ----
    f32x4 hcs, tOldr;
    bool dnr[4];
    bool all4 = true;
    #pragma unroll
    for (int r = 0; r < 4; ++r) {
      bool d = tcur[r] >= t1v - 1e-6f;
      dnr[r] = d;
      all4 &= d;
      hcs[r] = d ? 0.0f : fminf(hcur[r], t1v - tcur[r]);
      tOldr[r] = tcur[r];
    }
    if (__ballot(all4) == ~0ull) break;   // all valid trajectories done

    f32x4 p1;
    #pragma unroll
    for (int r = 0; r < 4; ++r) p1[r] = fmaf(hcs[r], A21 * uu[0][r], p_y[r]);
    evalF(p1, kk[1], uu[1]);

    #pragma unroll
    for (int r = 0; r < 4; ++r)
      p1[r] = fmaf(hcs[r], fmaf(A32, uu[1][r], A31 * uu[0][r]), p_y[r]);
    evalF(p1, kk[2], uu[2]);

    #pragma unroll
    for (int r = 0; r < 4; ++r)
      p1[r] = fmaf(hcs[r], fmaf(A43, uu[2][r], fmaf(A42, uu[1][r], A41 * uu[0][r])), p_y[r]);
    evalF(p1, kk[3], uu[3]);

    #pragma unroll
    for (int r = 0; r < 4; ++r)
      p1[r] = fmaf(hcs[r], fmaf(A54, uu[3][r], fmaf(A53, uu[2][r],
                  fmaf(A52, uu[1][r], A51 * uu[0][r]))), p_y[r]);
    evalF(p1, kk[4], uu[4]);

    #pragma unroll
    for (int r = 0; r < 4; ++r)
      p1[r] = fmaf(hcs[r], fmaf(A65, uu[4][r], fmaf(A64, uu[3][r], fmaf(A63, uu[2][r],
                  fmaf(A62, uu[1][r], A61 * uu[0][r])))), p_y[r]);
    evalF(p1, kk[5], uu[5]);

    f32x4 bu;
    #pragma unroll
    for (int r = 0; r < 4; ++r) {
      bu[r] = fmaf(B6, uu[5][r], fmaf(B5, uu[4][r], fmaf(B4, uu[3][r],
              fmaf(B3, uu[2][r], fmaf(B2, uu[1][r], B1 * uu[0][r])))));
      synr[r] = fmaf(hcs[r], fmaf(B6, kk[5][r], fmaf(B5, kk[4][r], fmaf(B4, kk[3][r],
                 fmaf(B3, kk[2][r], fmaf(B2, kk[1][r], B1 * kk[0][r]))))), syr[r]);
      p1[r] = fmaf(hcs[r], bu[r], p_y[r]);
    }
    // early-stash: interp state known pre-k7; drains behind evalF's barriers
    if (w0 && cact) {
      #pragma unroll
      for (int r = 0; r < 4; ++r) {
        int o = (row0 + r) * SD + col;
        sY[o] = syr[r];
        sYN[o] = synr[r];
        sK1[o] = kk[0][r];
      }
    }
    evalF(p1, kk[6], uu[6]);   // k7 (FSAL)

    // ---- error norm: per-lane rr^2, 4 xor-shuffle rounds over the 16-group ----
    f32x4 rr2;
    #pragma unroll
    for (int r = 0; r < 4; ++r) {
      float err = hcs[r] * fmaf(E7, kk[6][r], fmaf(E6, kk[5][r], fmaf(E5, kk[4][r],
                  fmaf(E4, kk[3][r], fmaf(E3, kk[2][r], fmaf(E2, kk[1][r], E1 * kk[0][r]))))));
      float sc = fmaf(1e-3f, fmaxf(fabsf(syr[r]), fabsf(synr[r])), 1e-6f);
      float rr = err / sc;
      rr2[r] = cact ? rr * rr : 0.0f;
    }
    #pragma unroll
    for (int m = 1; m < 16; m <<= 1) {
      #pragma unroll
      for (int r = 0; r < 4; ++r) rr2[r] += __shfl_xor(rr2[r], m, 64);
    }

    // ---- controller: registers, all lanes, fast exp/log factor ----
    bool okr[4];
    #pragma unroll
    for (int r = 0; r < 4; ++r) {
      float enorm = sqrtf(rr2[r] / 5.0f);
      float enc = fmaxf(enorm, 1e-10f);
      bool accept = enorm <= 1.0f;
      float factor = fminf(fmaxf(0.9f * __expf(-0.2f * __logf(enc)), 0.2f), 10.0f);
      bool ok = accept && !dnr[r];
      okr[r] = ok;
      tcur[r] = ok ? tcur[r] + hcs[r] : tcur[r];
      hcur[r] = dnr[r] ? hcur[r] : hcs[r] * factor;
    }

    // ---- small stash: k7 + control for interp; ONE tail barrier ----
    if (w0 && cact) {
      #pragma unroll
      for (int r = 0; r < 4; ++r) sK7[(row0 + r) * SD + col] = kk[6][r];
    }
    if (w0 && col == 0) {
      #pragma unroll
      for (int r = 0; r < 4; ++r) {
        int m2 = row0 + r;
        ctT[m2] = tOldr[r];
        ctH[m2] = hcs[r];
        ctN[m2] = tcur[r];
        ctO[m2] = okr[r] ? 1.0f : 0.0f;
      }
    }
    __syncthreads();

    // ---- cubic Hermite interpolation for save points in (t, t_next] ----
    {
      int tt = tid & 7, gg = tid >> 3;   // 8 trajs x 32 groups x 2 saves
      if (ctO[tt] != 0.0f) {
        float tOld = ctT[tt], hcv = ctH[tt], tNew = ctN[tt];
        float inv = 1.0f / fmaxf(hcv, 1e-12f);
        float yv[kDim], ynv[kDim], k1v[kDim], k7v[kDim];
        #pragma unroll
        for (int d = 0; d < kDim; ++d) {
          yv[d] = sY[tt * SD + d];
          ynv[d] = sYN[tt * SD + d];
          k1v[d] = hcv * sK1[tt * SD + d];
          k7v[d] = hcv * sK7[tt * SD + d];
        }
        #pragma unroll
        for (int q = 0; q < 2; ++q) {
          int n = 2 * gg + q;
          float te = sTe[n];
          if (te > tOld && te <= tNew + 1e-6f) {
            float sx = (te - tOld) * inv;
            float s2 = sx * sx, s3 = s2 * sx;
            float h00 = 2.f * s3 - 3.f * s2 + 1.f;
            float h10 = s3 - 2.f * s2 + sx;
            float h01 = -2.f * s3 + 3.f * s2;
            float h11 = s3 - s2;
            float* op = out + ((size_t)(bid * kTraj + tt) * kSave + n) * kDim;
            #pragma unroll
            for (int d = 0; d < kDim; ++d)
              op[d] = h00 * yv[d] + h10 * k1v[d] + h01 * ynv[d] + h11 * k7v[d];
          }
        }
      }
    }

    // ---- FSAL + state update (pure registers, no barrier) ----
    #pragma unroll
    for (int r = 0; r < 4; ++r) {
      if (okr[r]) {
        syr[r] = synr[r];
        kk[0][r] = kk[6][r];
        uu[0][r] = uu[6][r];
        p_y[r] = fmaf(hcs[r], bu[r], p_y[r]);   // p_ynew = W1*ynew + b1 (recursed)
      }
    }
  }
}

}  // namespace

extern "C" void kernel_launch(void* const* d_in, const int* in_sizes, int n_in,
                              void* d_out, int out_size, void* d_ws, size_t ws_size,
                              hipStream_t stream) {
  const float* y0 = (const float*)d_in[0];
  const float* te = (const float*)d_in[1];
  const float* W1 = (const float*)d_in[2];
  const float* b1 = (const float*)d_in[3];
  const float* W2 = (const float*)d_in[4];
  const float* b2 = (const float*)d_in[5];
  const float* W3 = (const float*)d_in[6];
  const float* b3 = (const float*)d_in[7];
  const float* W4 = (const float*)d_in[8];
  const float* b4 = (const float*)d_in[9];
  float* out = (float*)d_out;

  const int batch = in_sizes[0] / kDim;      // 4096
  const int blocks = batch / kTraj;          // 512 blocks -> 2 blocks/CU (TLP)
  hipLaunchKernelGGL(node_tsit5_kernel, dim3(blocks), dim3(kThreads), 0, stream,
                     y0, te, W1, b1, W2, b2, W3, b3, W4, b4, out);
}

// Round 14
// 107.390 us; speedup vs baseline: 1.1969x; 1.0996x over previous
//
#include <hip/hip_runtime.h>
#include <cmath>

namespace {

constexpr int kDim = 5;
constexpr int kSave = 64;
constexpr int kTraj = 16;      // trajectories per block (= MFMA M)
constexpr int kThreads = 256;  // 4 waves; wave w owns neuron tile [16w,16w+16)
constexpr int kMaxSteps = 64;
constexpr int HS = 72;         // f16 stride: activation planes (144 B)
constexpr int SD = 8;          // f32 stride: small state rows

typedef _Float16 half8 __attribute__((ext_vector_type(8)));
typedef float f32x4 __attribute__((ext_vector_type(4)));

__device__ __forceinline__ float softplusf(float x) {
  return fmaxf(x, 0.0f) + __logf(1.0f + __expf(-fabsf(x)));
}

__global__ __launch_bounds__(kThreads, 1)
void node_tsit5_kernel(const float* __restrict__ gy0,
                       const float* __restrict__ gte,
                       const float* __restrict__ gW1, const float* __restrict__ gb1,
                       const float* __restrict__ gW2, const float* __restrict__ gb2,
                       const float* __restrict__ gW3, const float* __restrict__ gb3,
                       const float* __restrict__ gW4, const float* __restrict__ gb4,
                       float* __restrict__ out) {
  const float A21 = 0.161f;
  const float A31 = -0.008480655492356989f, A32 = 0.335480655492357f;
  const float A41 = 2.8971530571054935f, A42 = -6.359448489975075f, A43 = 4.3622954328695815f;
  const float A51 = 5.325864828439257f, A52 = -11.748883564062828f, A53 = 7.4955393428898365f,
              A54 = -0.09249506636175525f;
  const float A61 = 5.86145544294642f, A62 = -12.92096931784711f, A63 = 8.159367898576159f,
              A64 = -0.071584973281401f, A65 = -0.028269050394068383f;
  const float B1 = 0.09646076681806523f, B2 = 0.01f, B3 = 0.4798896504144996f,
              B4 = 1.379008574103742f, B5 = -3.290069515436081f, B6 = 2.324710524099774f;
  const float E1 = -0.00178001105222577714f, E2 = -0.0008164344596567469f,
              E3 = 0.007880878010261995f, E4 = -0.1447110071732629f, E5 = 0.5823571654525552f,
              E6 = -0.45808210592918697f, E7 = 0.015151515151515152f;

  __shared__ __align__(16) _Float16 h0[kTraj * HS], l0[kTraj * HS];
  __shared__ __align__(16) _Float16 h1[kTraj * HS], l1[kTraj * HS];
  __shared__ __align__(16) _Float16 h2[kTraj * HS], l2[kTraj * HS];
  __shared__ float sTe[kSave];
  __shared__ float sY[kTraj * SD], sYN[kTraj * SD], sK1[kTraj * SD], sK7[kTraj * SD];
  __shared__ float ctT[kTraj], ctH[kTraj], ctN[kTraj], ctO[kTraj];

  const int tid = threadIdx.x;
  const int bid = blockIdx.x;
  const int w = tid >> 6;          // wave id = neuron tile
  const int ln = tid & 63;
  const int quad = ln >> 4;
  const int col = ln & 15;
  const int row0 = quad * 4;       // this lane's C-layout trajectories: row0+r
  const int nn = (w << 4) | col;
  const bool cact = col < kDim;    // C-lane carries dim d = col
  const bool w0 = (w == 0);

  // ---- one-time: weight B-frags + biases + fused M = W1*W4 ----
  half8 w2h[2], w3h[2], w4h[2], mfh[2];
  float w1r[kDim];
  #pragma unroll
  for (int d = 0; d < kDim; ++d) w1r[d] = gW1[nn * 5 + d];
  #pragma unroll
  for (int kf = 0; kf < 2; ++kf)
    #pragma unroll
    for (int j = 0; j < 8; ++j) {
      int kk2 = kf * 32 + quad * 8 + j;
      w2h[kf][j] = (_Float16)gW2[nn * 64 + kk2];
      w3h[kf][j] = (_Float16)gW3[nn * 64 + kk2];
      w4h[kf][j] = cact ? (_Float16)gW4[col * 64 + kk2] : (_Float16)0.0f;
      float m = 0.0f;
      #pragma unroll
      for (int d = 0; d < kDim; ++d) m = fmaf(w1r[d], gW4[d * 64 + kk2], m);
      mfh[kf][j] = (_Float16)m;
    }
  const float c1 = gb1[nn], c2 = gb2[nn], c3 = gb3[nn];
  const float c4 = cact ? gb4[col] : 0.0f;   // => k cols>=5 are exactly 0
  float cu = 0.0f;                            // (W1*b4)[nn]
  #pragma unroll
  for (int d = 0; d < kDim; ++d) cu = fmaf(w1r[d], gb4[d], cu);

  // ---- init LDS ----
  if (tid < kSave) sTe[tid] = gte[tid];
  if (tid < kTraj * kDim) {   // sY for the y0 output fill
    int t = tid & 15, d = tid >> 4;
    sY[t * SD + d] = gy0[(size_t)(bid * kTraj + t) * kDim + d];
  }
  {
    float* ob = out + (size_t)bid * kTraj * kSave * kDim;
    for (int idx = tid; idx < kTraj * kSave * kDim; idx += kThreads) ob[idx] = 0.0f;
  }

  // y-state (replicated across waves) + p_y = W1*y + b1 (per wave tile, f32)
  f32x4 syr = {0, 0, 0, 0}, synr = {0, 0, 0, 0}, kk[7], uu[7], p_y;
  #pragma unroll
  for (int r = 0; r < 4; ++r) {
    const float* yr = gy0 + (size_t)(bid * kTraj + row0 + r) * kDim;
    float acc = c1;
    #pragma unroll
    for (int d = 0; d < kDim; ++d) acc = fmaf(w1r[d], yr[d], acc);
    p_y[r] = acc;
    if (cact) syr[r] = yr[col];
  }
  __syncthreads();

  const float t0v = sTe[0];
  const float t1v = sTe[kSave - 1];

  // saves at/before t0 get y0 (same-lane overwrite later -> program order)
  {
    int tt = tid & 15, gg = tid >> 4;
    float yv[kDim];
    #pragma unroll
    for (int d = 0; d < kDim; ++d) yv[d] = sY[tt * SD + d];
    #pragma unroll
    for (int q = 0; q < 4; ++q) {
      int n = 4 * gg + q;
      if (sTe[n] <= t0v + 1e-6f) {
        float* op = out + ((size_t)(bid * kTraj + tt) * kSave + n) * kDim;
        #pragma unroll
        for (int d = 0; d < kDim; ++d) op[d] = yv[d];
      }
    }
  }

  // ---- stage A: softplus(pre1) -> h0/l0 (no barrier; caller barriers) ----
  auto stageA = [&](f32x4 pre1) {
    #pragma unroll
    for (int r = 0; r < 4; ++r) {
      float s = softplusf(pre1[r]);
      _Float16 hi = (_Float16)s;
      h0[(row0 + r) * HS + nn] = hi;
      l0[(row0 + r) * HS + nn] = (_Float16)(s - (float)hi);
    }
  };

  // ---- evalR: [L2 | b2 | L3 | b3 | final]; precondition: h0 written + barrier ----
  auto evalR = [&](f32x4& kOut, f32x4& uOut) {
    {  // L2: h0/l0 -> h1/l1
      half8 ah0 = *(const half8*)(h0 + col * HS + quad * 8);
      half8 ah1 = *(const half8*)(h0 + col * HS + 32 + quad * 8);
      half8 al0 = *(const half8*)(l0 + col * HS + quad * 8);
      half8 al1 = *(const half8*)(l0 + col * HS + 32 + quad * 8);
      f32x4 a = {c2, c2, c2, c2};
      f32x4 b = {0, 0, 0, 0};
      a = __builtin_amdgcn_mfma_f32_16x16x32_f16(ah0, w2h[0], a, 0, 0, 0);
      b = __builtin_amdgcn_mfma_f32_16x16x32_f16(al0, w2h[0], b, 0, 0, 0);
      a = __builtin_amdgcn_mfma_f32_16x16x32_f16(ah1, w2h[1], a, 0, 0, 0);
      b = __builtin_amdgcn_mfma_f32_16x16x32_f16(al1, w2h[1], b, 0, 0, 0);
      a += b;
      #pragma unroll
      for (int r = 0; r < 4; ++r) {
        float s = softplusf(a[r]);
        _Float16 hi = (_Float16)s;
        h1[(row0 + r) * HS + nn] = hi;
        l1[(row0 + r) * HS + nn] = (_Float16)(s - (float)hi);
      }
    }
    __syncthreads();   // b2
    {  // L3: h1/l1 -> h2/l2
      half8 ah0 = *(const half8*)(h1 + col * HS + quad * 8);
      half8 ah1 = *(const half8*)(h1 + col * HS + 32 + quad * 8);
      half8 al0 = *(const half8*)(l1 + col * HS + quad * 8);
      half8 al1 = *(const half8*)(l1 + col * HS + 32 + quad * 8);
      f32x4 a = {c3, c3, c3, c3};
      f32x4 b = {0, 0, 0, 0};
      a = __builtin_amdgcn_mfma_f32_16x16x32_f16(ah0, w3h[0], a, 0, 0, 0);
      b = __builtin_amdgcn_mfma_f32_16x16x32_f16(al0, w3h[0], b, 0, 0, 0);
      a = __builtin_amdgcn_mfma_f32_16x16x32_f16(ah1, w3h[1], a, 0, 0, 0);
      b = __builtin_amdgcn_mfma_f32_16x16x32_f16(al1, w3h[1], b, 0, 0, 0);
      a += b;
      #pragma unroll
      for (int r = 0; r < 4; ++r) {
        float s = softplusf(a[r]);
        _Float16 hi = (_Float16)s;
        h2[(row0 + r) * HS + nn] = hi;
        l2[(row0 + r) * HS + nn] = (_Float16)(s - (float)hi);
      }
    }
    __syncthreads();   // b3
    {  // final: k = W4*h3 + b4 (cols<5) and u = M*h3 + W1*b4 (this tile)
      half8 ah0 = *(const half8*)(h2 + col * HS + quad * 8);
      half8 ah1 = *(const half8*)(h2 + col * HS + 32 + quad * 8);
      half8 al0 = *(const half8*)(l2 + col * HS + quad * 8);
      half8 al1 = *(const half8*)(l2 + col * HS + 32 + quad * 8);
      f32x4 ka = {c4, c4, c4, c4};
      f32x4 kb = {0, 0, 0, 0};
      f32x4 ua = {cu, cu, cu, cu};
      f32x4 ub = {0, 0, 0, 0};
      ka = __builtin_amdgcn_mfma_f32_16x16x32_f16(ah0, w4h[0], ka, 0, 0, 0);
      kb = __builtin_amdgcn_mfma_f32_16x16x32_f16(al0, w4h[0], kb, 0, 0, 0);
      ua = __builtin_amdgcn_mfma_f32_16x16x32_f16(ah0, mfh[0], ua, 0, 0, 0);
      ub = __builtin_amdgcn_mfma_f32_16x16x32_f16(al0, mfh[0], ub, 0, 0, 0);
      ka = __builtin_amdgcn_mfma_f32_16x16x32_f16(ah1, w4h[1], ka, 0, 0, 0);
      kb = __builtin_amdgcn_mfma_f32_16x16x32_f16(al1, w4h[1], kb, 0, 0, 0);
      ua = __builtin_amdgcn_mfma_f32_16x16x32_f16(ah1, mfh[1], ua, 0, 0, 0);
      ub = __builtin_amdgcn_mfma_f32_16x16x32_f16(al1, mfh[1], ub, 0, 0, 0);
      kOut = ka + kb;
      uOut = ua + ub;
    }
  };

  // k1 = f(y0); FSAL thereafter
  stageA(p_y);
  __syncthreads();
  evalR(kk[0], uu[0]);

  // control state in registers (replicated bit-identically across lanes/waves)
  f32x4 tcur = {t0v, t0v, t0v, t0v};
  f32x4 hcur = {0.1f, 0.1f, 0.1f, 0.1f};
  f32x4 hcs, tOldr;
  bool dnr[4];
  bool alldone;

  auto head = [&]() {
    bool all4 = true;
    #pragma unroll
    for (int r = 0; r < 4; ++r) {
      bool d = tcur[r] >= t1v - 1e-6f;
      dnr[r] = d;
      all4 &= d;
      hcs[r] = d ? 0.0f : fminf(hcur[r], t1v - tcur[r]);
      tOldr[r] = tcur[r];
    }
    alldone = (__ballot(all4) == ~0ull);
  };

  // prologue: head for step 0 + stage A of its k2-eval
  head();
  if (!alldone) {
    f32x4 p1;
    #pragma unroll
    for (int r = 0; r < 4; ++r) p1[r] = fmaf(hcs[r], A21 * uu[0][r], p_y[r]);
    stageA(p1);
    __syncthreads();
  }

  for (int step = 0; step < kMaxSteps && !alldone; ++step) {
    // precondition: h0/l0 for this step's k2-eval written, barrier passed
    f32x4 p1;
    evalR(kk[1], uu[1]);

    #pragma unroll
    for (int r = 0; r < 4; ++r)
      p1[r] = fmaf(hcs[r], fmaf(A32, uu[1][r], A31 * uu[0][r]), p_y[r]);
    stageA(p1); __syncthreads(); evalR(kk[2], uu[2]);

    #pragma unroll
    for (int r = 0; r < 4; ++r)
      p1[r] = fmaf(hcs[r], fmaf(A43, uu[2][r], fmaf(A42, uu[1][r], A41 * uu[0][r])), p_y[r]);
    stageA(p1); __syncthreads(); evalR(kk[3], uu[3]);

    #pragma unroll
    for (int r = 0; r < 4; ++r)
      p1[r] = fmaf(hcs[r], fmaf(A54, uu[3][r], fmaf(A53, uu[2][r],
                  fmaf(A52, uu[1][r], A51 * uu[0][r]))), p_y[r]);
    stageA(p1); __syncthreads(); evalR(kk[4], uu[4]);

    #pragma unroll
    for (int r = 0; r < 4; ++r)
      p1[r] = fmaf(hcs[r], fmaf(A65, uu[4][r], fmaf(A64, uu[3][r], fmaf(A63, uu[2][r],
                  fmaf(A62, uu[1][r], A61 * uu[0][r])))), p_y[r]);
    stageA(p1); __syncthreads(); evalR(kk[5], uu[5]);

    f32x4 bu;
    #pragma unroll
    for (int r = 0; r < 4; ++r) {
      bu[r] = fmaf(B6, uu[5][r], fmaf(B5, uu[4][r], fmaf(B4, uu[3][r],
              fmaf(B3, uu[2][r], fmaf(B2, uu[1][r], B1 * uu[0][r])))));
      synr[r] = fmaf(hcs[r], fmaf(B6, kk[5][r], fmaf(B5, kk[4][r], fmaf(B4, kk[3][r],
                 fmaf(B3, kk[2][r], fmaf(B2, kk[1][r], B1 * kk[0][r]))))), syr[r]);
      p1[r] = fmaf(hcs[r], bu[r], p_y[r]);
    }
    // early-stash: interp state known pre-k7; drains behind evalR's barriers
    if (w0 && cact) {
      #pragma unroll
      for (int r = 0; r < 4; ++r) {
        int o = (row0 + r) * SD + col;
        sY[o] = syr[r];
        sYN[o] = synr[r];
        sK1[o] = kk[0][r];
      }
    }
    stageA(p1); __syncthreads(); evalR(kk[6], uu[6]);   // k7 (FSAL)

    // ---- error norm: per-lane rr^2, 4 xor-shuffle rounds over the 16-group ----
    f32x4 rr2;
    #pragma unroll
    for (int r = 0; r < 4; ++r) {
      float err = hcs[r] * fmaf(E7, kk[6][r], fmaf(E6, kk[5][r], fmaf(E5, kk[4][r],
                  fmaf(E4, kk[3][r], fmaf(E3, kk[2][r], fmaf(E2, kk[1][r], E1 * kk[0][r]))))));
      float sc = fmaf(1e-3f, fmaxf(fabsf(syr[r]), fabsf(synr[r])), 1e-6f);
      float rr = err / sc;
      rr2[r] = cact ? rr * rr : 0.0f;
    }
    #pragma unroll
    for (int m = 1; m < 16; m <<= 1) {
      #pragma unroll
      for (int r = 0; r < 4; ++r) rr2[r] += __shfl_xor(rr2[r], m, 64);
    }

    // ---- controller (identical math to R10) ----
    bool okr[4];
    #pragma unroll
    for (int r = 0; r < 4; ++r) {
      float enorm = sqrtf(rr2[r] / 5.0f);
      float enc = fmaxf(enorm, 1e-10f);
      bool accept = enorm <= 1.0f;
      float factor = fminf(fmaxf(0.9f * __expf(-0.2f * __logf(enc)), 0.2f), 10.0f);
      bool ok = accept && !dnr[r];
      okr[r] = ok;
      tcur[r] = ok ? tcur[r] + hcs[r] : tcur[r];
      hcur[r] = dnr[r] ? hcur[r] : hcs[r] * factor;
    }

    // ---- stash k7 + control (current step's tOldr/hcs/tcur) ----
    if (w0 && cact) {
      #pragma unroll
      for (int r = 0; r < 4; ++r) sK7[(row0 + r) * SD + col] = kk[6][r];
    }
    if (w0 && col == 0) {
      #pragma unroll
      for (int r = 0; r < 4; ++r) {
        int m2 = row0 + r;
        ctT[m2] = tOldr[r];
        ctH[m2] = hcs[r];
        ctN[m2] = tcur[r];
        ctO[m2] = okr[r] ? 1.0f : 0.0f;
      }
    }

    // ---- FSAL + state update (registers) ----
    #pragma unroll
    for (int r = 0; r < 4; ++r) {
      if (okr[r]) {
        syr[r] = synr[r];
        kk[0][r] = kk[6][r];
        uu[0][r] = uu[6][r];
        p_y[r] = fmaf(hcs[r], bu[r], p_y[r]);   // p_ynew = W1*ynew + b1 (recursed)
      }
    }

    // ---- next step's head + stage A (pre-barrier), then ONE merged barrier ----
    head();
    if (!alldone) {
      f32x4 pn;
      #pragma unroll
      for (int r = 0; r < 4; ++r) pn[r] = fmaf(hcs[r], A21 * uu[0][r], p_y[r]);
      stageA(pn);   // WAR on h0 safe: last h0 reads were >=2 barriers upstream
    }
    __syncthreads();   // orders stash + h0 writes; interp fills the b1 shadow

    // ---- cubic Hermite interpolation for save points in (t, t_next] ----
    {
      int tt = tid & 15, gg = tid >> 4;
      if (ctO[tt] != 0.0f) {
        float tOld = ctT[tt], hcv = ctH[tt], tNew = ctN[tt];
        float inv = 1.0f / fmaxf(hcv, 1e-12f);
        float yv[kDim], ynv[kDim], k1v[kDim], k7v[kDim];
        #pragma unroll
        for (int d = 0; d < kDim; ++d) {
          yv[d] = sY[tt * SD + d];
          ynv[d] = sYN[tt * SD + d];
          k1v[d] = hcv * sK1[tt * SD + d];
          k7v[d] = hcv * sK7[tt * SD + d];
        }
        #pragma unroll
        for (int q = 0; q < 4; ++q) {
          int n = 4 * gg + q;
          float te = sTe[n];
          if (te > tOld && te <= tNew + 1e-6f) {
            float sx = (te - tOld) * inv;
            float s2 = sx * sx, s3 = s2 * sx;
            float h00 = 2.f * s3 - 3.f * s2 + 1.f;
            float h10 = s3 - 2.f * s2 + sx;
            float h01 = -2.f * s3 + 3.f * s2;
            float h11 = s3 - s2;
            float* op = out + ((size_t)(bid * kTraj + tt) * kSave + n) * kDim;
            #pragma unroll
            for (int d = 0; d < kDim; ++d)
              op[d] = h00 * yv[d] + h10 * k1v[d] + h01 * ynv[d] + h11 * k7v[d];
          }
        }
      }
    }
  }
}

}  // namespace

extern "C" void kernel_launch(void* const* d_in, const int* in_sizes, int n_in,
                              void* d_out, int out_size, void* d_ws, size_t ws_size,
                              hipStream_t stream) {
  const float* y0 = (const float*)d_in[0];
  const float* te = (const float*)d_in[1];
  const float* W1 = (const float*)d_in[2];
  const float* b1 = (const float*)d_in[3];
  const float* W2 = (const float*)d_in[4];
  const float* b2 = (const float*)d_in[5];
  const float* W3 = (const float*)d_in[6];
  const float* b3 = (const float*)d_in[7];
  const float* W4 = (const float*)d_in[8];
  const float* b4 = (const float*)d_in[9];
  float* out = (float*)d_out;

  const int batch = in_sizes[0] / kDim;      // 4096
  const int blocks = batch / kTraj;          // 256 blocks x 4 waves = 1 block/CU
  hipLaunchKernelGGL(node_tsit5_kernel, dim3(blocks), dim3(kThreads), 0, stream,
                     y0, te, W1, b1, W2, b2, W3, b3, W4, b4, out);
}